// Round 2
// baseline (34.762 us; speedup 1.0000x reference)
//
#include <hip/hip_runtime.h>

#define FD 32        // feature dim
#define NDD 16       // number of d-pairs
#define TILE 128     // output tile edge per block
#define PLANE 260    // floats per dd-plane: 64 chunks * 4 floats + 4 pad (1040 B, 16B-aligned)

// packed dual-fp32 add (b is pre-negated in LDS, so this is a-b)
__device__ __forceinline__ float2 pk_add(float2 a, float2 b) {
    float2 r;
    asm("v_pk_add_f32 %0, %1, %2" : "=v"(r) : "v"(a), "v"(b));
    return r;
}
// acc = max(acc, |x|, |y|) in ONE VALU inst (abs is a free VOP3 input modifier)
__device__ __forceinline__ float max3abs(float a, float x, float y) {
    float r;
    asm("v_max3_f32 %0, %1, abs(%2), abs(%3)" : "=v"(r) : "v"(a), "v"(x), "v"(y));
    return r;
}

__global__ __launch_bounds__(256) void cheb_kernel(
    const float* __restrict__ A, const float* __restrict__ B,
    float* __restrict__ C, int M)
{
    // Layout: plane per d-pair dd; within a plane, 2-row "chunks" of float2 (d0,d1),
    // chunk c placed at float offset perm(c)*4 with perm(c) = c ^ (c>>3) (XOR bank swizzle).
    __shared__ __align__(16) float sA[NDD * PLANE];
    __shared__ __align__(16) float sB[NDD * PLANE];

    const int tid = threadIdx.x;
    const int r0 = blockIdx.y * TILE;   // A rows / output rows
    const int c0 = blockIdx.x * TILE;   // B rows / output cols

    // ---- Stage: 128 rows x 32 floats per matrix = 1024 float4; 256 threads -> 4 each.
#pragma unroll
    for (int k = 0; k < 4; ++k) {
        const int idx = tid + k * 256;      // 0..1023
        const int row = idx >> 3;           // 0..127
        const int dq  = (idx & 7) * 4;      // 0,4,...,28
        const int c   = row >> 1;
        const int pc  = c ^ (c >> 3);
        const int base = (dq >> 1) * PLANE + pc * 4 + (row & 1) * 2;
        const float4 va = *reinterpret_cast<const float4*>(A + (size_t)(r0 + row) * FD + dq);
        sA[base + 0] = va.x;  sA[base + 1] = va.y;           // dd = dq/2
        sA[base + PLANE + 0] = va.z;  sA[base + PLANE + 1] = va.w;  // dd = dq/2+1
        const float4 vb = *reinterpret_cast<const float4*>(B + (size_t)(c0 + row) * FD + dq);
        sB[base + 0] = -vb.x;  sB[base + 1] = -vb.y;         // store NEGATED B
        sB[base + PLANE + 0] = -vb.z;  sB[base + PLANE + 1] = -vb.w;
    }
    __syncthreads();

    const int tx = tid & 15;   // column group selector
    const int ty = tid >> 4;   // row group selector
    // Thread owns rows r0+ty*8..+7, cols {c0+tx*4..+3} U {c0+64+tx*4..+3} (split for
    // perfectly coalesced float4 stores).

    float acc[8][8];
#pragma unroll
    for (int i = 0; i < 8; ++i)
#pragma unroll
        for (int j = 0; j < 8; ++j)
            acc[i][j] = 0.0f;

    // Swizzled chunk offsets (loop-invariant, hoisted by compiler).
    int swA[4], swB[4];
#pragma unroll
    for (int k = 0; k < 4; ++k) {
        const int cA = ty * 4 + k;                       // A chunks: rows ty*8..+7
        swA[k] = (cA ^ (cA >> 3)) * 4;
        const int cB = ((k & 2) ? 32 : 0) + 2 * tx + (k & 1);  // B chunks for split cols
        swB[k] = (cB ^ (cB >> 3)) * 4;
    }

#pragma unroll
    for (int dd = 0; dd < NDD; ++dd) {
        const float* pA = sA + dd * PLANE;
        const float* pB = sB + dd * PLANE;
        float2 pa[8], pb[8];
#pragma unroll
        for (int k = 0; k < 4; ++k) {
            const float4 v = *reinterpret_cast<const float4*>(pA + swA[k]);
            pa[2 * k]     = make_float2(v.x, v.y);
            pa[2 * k + 1] = make_float2(v.z, v.w);
        }
#pragma unroll
        for (int k = 0; k < 4; ++k) {
            const float4 v = *reinterpret_cast<const float4*>(pB + swB[k]);
            pb[2 * k]     = make_float2(v.x, v.y);
            pb[2 * k + 1] = make_float2(v.z, v.w);
        }
#pragma unroll
        for (int i = 0; i < 8; ++i)
#pragma unroll
            for (int j = 0; j < 8; ++j) {
                const float2 d2 = pk_add(pa[i], pb[j]);   // a - b (packed, 2 d's)
                acc[i][j] = max3abs(acc[i][j], d2.x, d2.y);
            }
    }

    // ---- Write: 8 rows x 2 float4 groups; each instruction is 256B-contiguous per ty-row.
#pragma unroll
    for (int i = 0; i < 8; ++i) {
        const size_t rowoff = (size_t)(r0 + ty * 8 + i) * M;
        float4 o0, o1;
        o0.x = acc[i][0]; o0.y = acc[i][1]; o0.z = acc[i][2]; o0.w = acc[i][3];
        o1.x = acc[i][4]; o1.y = acc[i][5]; o1.z = acc[i][6]; o1.w = acc[i][7];
        *reinterpret_cast<float4*>(C + rowoff + c0 + tx * 4) = o0;
        *reinterpret_cast<float4*>(C + rowoff + c0 + 64 + tx * 4) = o1;
    }
}

extern "C" void kernel_launch(void* const* d_in, const int* in_sizes, int n_in,
                              void* d_out, int out_size, void* d_ws, size_t ws_size,
                              hipStream_t stream) {
    const float* A = (const float*)d_in[0];
    const float* B = (const float*)d_in[1];
    float* C = (float*)d_out;
    const int N = in_sizes[0] / FD;   // 4096
    const int M = in_sizes[1] / FD;   // 4096
    dim3 grid(M / TILE, N / TILE);    // 32 x 32 tiles
    cheb_kernel<<<grid, 256, 0, stream>>>(A, B, C, M);
}